// Round 1
// baseline (316.921 us; speedup 1.0000x reference)
//
#include <hip/hip_runtime.h>

// SLAM layer: out[1,T,M,E,1] = (main[T,M,K] @ relu(x_aux[K,T,Da] @ W[Da,E] + b)[K,T,E] per t)
// T=128, M=512, K=256, Da=256, E=512. All-bf16-MFMA, no-LDS fragment-direct design.

typedef __attribute__((ext_vector_type(8))) short  bf16x8;   // 8 bf16 = 4 VGPRs (MFMA A/B frag)
typedef __attribute__((ext_vector_type(4))) float  f32x4;    // MFMA C/D frag
typedef __attribute__((ext_vector_type(4))) unsigned int uint4v;

#define T_DIM 128
#define M_DIM 512
#define K_DIM 256
#define DA    256
#define DENSE 512
// aux intermediate chunk layout: element (t,k,e) -> t*131072 + (k>>3)*4096 + e*8 + (k&7)  (bf16)
#define AUX_T_STRIDE (K_DIM * DENSE)      // 131072 elements per t
#define CHUNK_G_STRIDE (DENSE * 8)        // 4096 elements per k-group of 8

__device__ __forceinline__ unsigned short f2bf(float f) {
    unsigned u = __builtin_bit_cast(unsigned, f);
    unsigned r = (u + 0x7fffu + ((u >> 16) & 1u)) >> 16;   // RNE
    return (unsigned short)r;
}
__device__ __forceinline__ unsigned pack2(float lo, float hi) {
    return (unsigned)f2bf(lo) | ((unsigned)f2bf(hi) << 16);
}

// ---------------- Kernel 0: W [Da][E] f32 -> Wc bf16 chunks [g=Da/8][E][8] ----------------
__global__ __launch_bounds__(256) void wchunk_kernel(const float* __restrict__ W,
                                                     unsigned short* __restrict__ Wc) {
    int c = blockIdx.x * 256 + threadIdx.x;   // chunk id = g*DENSE + e; 32*512 = 16384 chunks
    int g = c >> 9;
    int e = c & 511;
    float f[8];
#pragma unroll
    for (int j = 0; j < 8; ++j) f[j] = W[(g * 8 + j) * DENSE + e];
    uint4v w;
    w.x = pack2(f[0], f[1]); w.y = pack2(f[2], f[3]);
    w.z = pack2(f[4], f[5]); w.w = pack2(f[6], f[7]);
    *reinterpret_cast<uint4v*>(Wc + (size_t)c * 8) = w;
}

// ---------------- Kernel 1: aux GEMM -------------------------------------------------------
// rows r' = t*256 + k (k fastest so acc regs = 4 consecutive k -> chunk-layout stores),
// cols e. A-op = x_aux rows (f32->bf16 in-reg), B-op = Wc chunks. Epilogue: +bias, relu,
// pack 4 bf16 -> 8B store into aux chunk layout.
__global__ __launch_bounds__(256) void aux_kernel(const float* __restrict__ xaux,
                                                  const unsigned short* __restrict__ Wc,
                                                  const float* __restrict__ bias,
                                                  unsigned short* __restrict__ auxc) {
    const int eb = blockIdx.x * 128;          // e block (4)
    const int rb = blockIdx.y;                // row block (256): 128 rows = one t, half the k
    const int t  = rb >> 1;
    const int kb = (rb & 1) * 128;
    const int lane = threadIdx.x & 63, wid = threadIdx.x >> 6;
    const int wk = (wid & 1) * 64;            // wave k-half
    const int we = (wid >> 1) * 64;           // wave e-half
    const int l15 = lane & 15, lg = lane >> 4;

    f32x4 acc[4][4];
#pragma unroll
    for (int i = 0; i < 4; ++i)
#pragma unroll
        for (int j = 0; j < 4; ++j) acc[i][j] = (f32x4)0.0f;

#pragma unroll
    for (int ds = 0; ds < DA / 32; ++ds) {
        bf16x8 wf[4];
#pragma unroll
        for (int j = 0; j < 4; ++j) {
            int e = eb + we + j * 16 + l15;
            wf[j] = *reinterpret_cast<const bf16x8*>(Wc + (size_t)(ds * 4 + lg) * CHUNK_G_STRIDE + (size_t)e * 8);
        }
        bf16x8 xf[4];
#pragma unroll
        for (int i = 0; i < 4; ++i) {
            int k = kb + wk + i * 16 + l15;
            const float* p = xaux + ((size_t)k * T_DIM + t) * DA + ds * 32 + lg * 8;
            f32x4 f0 = *reinterpret_cast<const f32x4*>(p);
            f32x4 f1 = *reinterpret_cast<const f32x4*>(p + 4);
            uint4v w;
            w.x = pack2(f0.x, f0.y); w.y = pack2(f0.z, f0.w);
            w.z = pack2(f1.x, f1.y); w.w = pack2(f1.z, f1.w);
            xf[i] = __builtin_bit_cast(bf16x8, w);
        }
#pragma unroll
        for (int i = 0; i < 4; ++i)
#pragma unroll
            for (int j = 0; j < 4; ++j)
                acc[i][j] = __builtin_amdgcn_mfma_f32_16x16x32_bf16(xf[i], wf[j], acc[i][j], 0, 0, 0);
    }

#pragma unroll
    for (int i = 0; i < 4; ++i) {
        int k0 = kb + wk + i * 16 + lg * 4;   // 4 acc regs = k0..k0+3; k0%4==0, k0%8 in {0,4}
#pragma unroll
        for (int j = 0; j < 4; ++j) {
            int e = eb + we + j * 16 + l15;
            float bv = bias[e];
            float v0 = fmaxf(acc[i][j].x + bv, 0.0f);
            float v1 = fmaxf(acc[i][j].y + bv, 0.0f);
            float v2 = fmaxf(acc[i][j].z + bv, 0.0f);
            float v3 = fmaxf(acc[i][j].w + bv, 0.0f);
            uint2 o; o.x = pack2(v0, v1); o.y = pack2(v2, v3);
            size_t idx = (size_t)t * AUX_T_STRIDE + (size_t)(k0 >> 3) * CHUNK_G_STRIDE
                       + (size_t)e * 8 + (k0 & 7);
            *reinterpret_cast<uint2*>(auxc + idx) = o;   // 8B aligned (k0&7 in {0,4})
        }
    }
}

// ---------------- Kernel 2: main GEMM (batched over t) -------------------------------------
// Swapped orientation: D[e][m] = sum_k aux[k][e] * main[m][k].
// A-op = aux chunks (row=e, 8 consec k contiguous), B-op = main rows (f32->bf16 in-reg).
// D: row=e=(lane>>4)*4+reg (4 consecutive e -> float4 store), col=m=lane&15.
__global__ __launch_bounds__(256) void main_kernel(const float* __restrict__ xmain,
                                                   const unsigned short* __restrict__ auxc,
                                                   float* __restrict__ out) {
    const int eb = blockIdx.x * 128;
    const int mb = blockIdx.y * 128;
    const int t  = blockIdx.z;
    const int lane = threadIdx.x & 63, wid = threadIdx.x >> 6;
    const int wm = (wid & 1) * 64;
    const int we = (wid >> 1) * 64;
    const int l15 = lane & 15, lg = lane >> 4;

    const float* At = xmain + (size_t)t * M_DIM * K_DIM;
    const unsigned short* Bt = auxc + (size_t)t * AUX_T_STRIDE;

    f32x4 acc[4][4];
#pragma unroll
    for (int i = 0; i < 4; ++i)
#pragma unroll
        for (int j = 0; j < 4; ++j) acc[i][j] = (f32x4)0.0f;

#pragma unroll
    for (int ks = 0; ks < K_DIM / 32; ++ks) {
        bf16x8 af[4];
#pragma unroll
        for (int i = 0; i < 4; ++i) {
            int e = eb + we + i * 16 + l15;
            af[i] = *reinterpret_cast<const bf16x8*>(Bt + (size_t)(ks * 4 + lg) * CHUNK_G_STRIDE + (size_t)e * 8);
        }
        bf16x8 mf[4];
#pragma unroll
        for (int j = 0; j < 4; ++j) {
            int m = mb + wm + j * 16 + l15;
            const float* p = At + (size_t)m * K_DIM + ks * 32 + lg * 8;
            f32x4 f0 = *reinterpret_cast<const f32x4*>(p);
            f32x4 f1 = *reinterpret_cast<const f32x4*>(p + 4);
            uint4v w;
            w.x = pack2(f0.x, f0.y); w.y = pack2(f0.z, f0.w);
            w.z = pack2(f1.x, f1.y); w.w = pack2(f1.z, f1.w);
            mf[j] = __builtin_bit_cast(bf16x8, w);
        }
#pragma unroll
        for (int i = 0; i < 4; ++i)
#pragma unroll
            for (int j = 0; j < 4; ++j)
                acc[i][j] = __builtin_amdgcn_mfma_f32_16x16x32_bf16(af[i], mf[j], acc[i][j], 0, 0, 0);
    }

#pragma unroll
    for (int i = 0; i < 4; ++i) {
        int e0 = eb + we + i * 16 + lg * 4;   // 4 consecutive e
#pragma unroll
        for (int j = 0; j < 4; ++j) {
            int m = mb + wm + j * 16 + l15;
            *reinterpret_cast<f32x4*>(out + (size_t)t * M_DIM * DENSE + (size_t)m * DENSE + e0) = acc[i][j];
        }
    }
}

extern "C" void kernel_launch(void* const* d_in, const int* in_sizes, int n_in,
                              void* d_out, int out_size, void* d_ws, size_t ws_size,
                              hipStream_t stream) {
    const float* x_main = (const float*)d_in[0];   // [1,128,512,256]
    const float* x_aux  = (const float*)d_in[1];   // [256,128,256]
    const float* W      = (const float*)d_in[2];   // [256,512]
    const float* b      = (const float*)d_in[3];   // [512]
    float* out = (float*)d_out;                    // [1,128,512,512,1]

    unsigned short* Wc   = (unsigned short*)d_ws;                       // 256 KiB
    unsigned short* auxc = (unsigned short*)((char*)d_ws + (1 << 19));  // 33.6 MiB

    wchunk_kernel<<<64, 256, 0, stream>>>(W, Wc);
    aux_kernel<<<dim3(4, 256), 256, 0, stream>>>(x_aux, Wc, b, auxc);
    main_kernel<<<dim3(4, 4, 128), 256, 0, stream>>>(x_main, auxc, out);
}

// Round 2
// 300.219 us; speedup vs baseline: 1.0556x; 1.0556x over previous
//
#include <hip/hip_runtime.h>

// SLAM layer: out[1,T,M,E,1] = (main[T,M,K] @ relu(x_aux[K,T,Da] @ W[Da,E] + b)[K,T,E] per t)
// T=128, M=512, K=256, Da=256, E=512. All-bf16-MFMA.
// R2: aux rebuilt with LDS staging (x_aux read once, coalesced row loads);
//     main gets register double-buffer prefetch + XCD-aware t-grouping swizzle.

typedef __attribute__((ext_vector_type(8))) short  bf16x8;   // 8 bf16 = 4 VGPRs (MFMA A/B frag)
typedef __attribute__((ext_vector_type(4))) float  f32x4;    // MFMA C/D frag
typedef __attribute__((ext_vector_type(4))) unsigned int uint4v;
typedef __attribute__((ext_vector_type(2))) unsigned int uint2v;

#define T_DIM 128
#define M_DIM 512
#define K_DIM 256
#define DA    256
#define DENSE 512
// aux intermediate chunk layout: (t,k,e) -> t*131072 + (k>>3)*4096 + e*8 + (k&7)  (bf16)
#define AUX_T_STRIDE (K_DIM * DENSE)      // 131072 elements per t
#define CHUNK_G_STRIDE (DENSE * 8)        // 4096 elements per k-group of 8

__device__ __forceinline__ unsigned short f2bf(float f) {
    unsigned u = __builtin_bit_cast(unsigned, f);
    unsigned r = (u + 0x7fffu + ((u >> 16) & 1u)) >> 16;   // RNE
    return (unsigned short)r;
}
__device__ __forceinline__ unsigned pack2(float lo, float hi) {
    return (unsigned)f2bf(lo) | ((unsigned)f2bf(hi) << 16);
}

// ---------------- Kernel 0: W [Da][E] f32 -> Wc bf16 chunks [g=Da/8][E][8] ----------------
__global__ __launch_bounds__(256) void wchunk_kernel(const float* __restrict__ W,
                                                     unsigned short* __restrict__ Wc) {
    int c = blockIdx.x * 256 + threadIdx.x;   // chunk id = g*DENSE + e
    int g = c >> 9;
    int e = c & 511;
    float f[8];
#pragma unroll
    for (int j = 0; j < 8; ++j) f[j] = W[(g * 8 + j) * DENSE + e];
    uint4v w;
    w.x = pack2(f[0], f[1]); w.y = pack2(f[2], f[3]);
    w.z = pack2(f[4], f[5]); w.w = pack2(f[6], f[7]);
    *reinterpret_cast<uint4v*>(Wc + (size_t)c * 8) = w;
}

// ---------------- Kernel 1: aux GEMM v2 ----------------------------------------------------
// Block = (t, k-half): 128 k x 512 e, 512 threads (8 waves: 2 k-halves x 4 e-quarters).
// x_aux rows staged to LDS once (coalesced 1KB rows, one wave per row), so x_aux is read
// exactly once from HBM. Wc is L2-resident. Double-buffered Wc fragment prefetch.
__global__ __launch_bounds__(512) void aux_kernel(const float* __restrict__ xaux,
                                                  const unsigned short* __restrict__ Wc,
                                                  const float* __restrict__ bias,
                                                  unsigned short* __restrict__ auxc) {
    __shared__ unsigned short xa[128][264];   // 264 = 256 + 8 pad: 528B row stride -> 2-way banks
    const int kb = blockIdx.x * 128;
    const int t  = blockIdx.y;
    const int tid = threadIdx.x;
    const int lane = tid & 63, wid = tid >> 6;

    // ---- stage x_aux[t][kb..kb+128][0..256) -> LDS bf16 ----
    {
        const int d0 = (tid & 63) * 4;        // lane covers 4 floats (16B) of a row
        const int kr = tid >> 6;              // wave id = row within group of 8
#pragma unroll
        for (int p = 0; p < 16; ++p) {
            int k = p * 8 + kr;
            const float* src = xaux + ((size_t)(kb + k) * T_DIM + t) * DA + d0;
            f32x4 v = *reinterpret_cast<const f32x4*>(src);
            uint2v o; o.x = pack2(v.x, v.y); o.y = pack2(v.z, v.w);
            *reinterpret_cast<uint2v*>(&xa[k][d0]) = o;
        }
    }
    __syncthreads();

    const int wk = (wid & 1) * 64;            // wave k-half within block's 128 k
    const int we = (wid >> 1) * 128;          // wave e-quarter (128 e)
    const int l15 = lane & 15, lg = lane >> 4;

    f32x4 acc[4][8];
#pragma unroll
    for (int i = 0; i < 4; ++i)
#pragma unroll
        for (int j = 0; j < 8; ++j) acc[i][j] = (f32x4)0.0f;

#define AUX_LOAD_WF(dst, dsv)                                                              \
    do {                                                                                   \
        _Pragma("unroll") for (int j = 0; j < 8; ++j) {                                    \
            int e = we + j * 16 + l15;                                                     \
            dst[j] = *reinterpret_cast<const bf16x8*>(                                     \
                Wc + (size_t)((dsv) * 4 + lg) * CHUNK_G_STRIDE + (size_t)e * 8);           \
        }                                                                                  \
    } while (0)

#define AUX_COMPUTE(wfc, dsv)                                                              \
    do {                                                                                   \
        bf16x8 xf[4];                                                                      \
        _Pragma("unroll") for (int i = 0; i < 4; ++i)                                      \
            xf[i] = *reinterpret_cast<const bf16x8*>(&xa[wk + i * 16 + l15][(dsv) * 32 + lg * 8]); \
        _Pragma("unroll") for (int i = 0; i < 4; ++i)                                      \
            _Pragma("unroll") for (int j = 0; j < 8; ++j)                                  \
                acc[i][j] = __builtin_amdgcn_mfma_f32_16x16x32_bf16(xf[i], wfc[j], acc[i][j], 0, 0, 0); \
    } while (0)

    bf16x8 wfA[8], wfB[8];
    AUX_LOAD_WF(wfA, 0);
#pragma unroll
    for (int ds = 0; ds < 8; ds += 2) {
        AUX_LOAD_WF(wfB, ds + 1);
        AUX_COMPUTE(wfA, ds);
        if (ds + 2 < 8) { AUX_LOAD_WF(wfA, ds + 2); }
        AUX_COMPUTE(wfB, ds + 1);
    }

    // ---- epilogue: +bias, relu, pack 4 bf16 -> chunk-layout store ----
#pragma unroll
    for (int i = 0; i < 4; ++i) {
        int k0 = kb + wk + i * 16 + lg * 4;   // 4 acc regs = 4 consecutive k; k0&7 in {0,4}
#pragma unroll
        for (int j = 0; j < 8; ++j) {
            int e = we + j * 16 + l15;
            float bv = bias[e];
            float v0 = fmaxf(acc[i][j].x + bv, 0.0f);
            float v1 = fmaxf(acc[i][j].y + bv, 0.0f);
            float v2 = fmaxf(acc[i][j].z + bv, 0.0f);
            float v3 = fmaxf(acc[i][j].w + bv, 0.0f);
            uint2 o; o.x = pack2(v0, v1); o.y = pack2(v2, v3);
            size_t idx = (size_t)t * AUX_T_STRIDE + (size_t)(k0 >> 3) * CHUNK_G_STRIDE
                       + (size_t)e * 8 + (k0 & 7);
            *reinterpret_cast<uint2*>(auxc + idx) = o;
        }
    }
#undef AUX_LOAD_WF
#undef AUX_COMPUTE
}

// ---------------- Kernel 2: main GEMM v2 (batched over t) ----------------------------------
// Swapped orientation: D[e][m] = sum_k aux[k][e] * main[m][k].
// Register double-buffer over K-steps (2 load-sets in flight) + XCD swizzle so all 16
// blocks of a given t run on the same XCD (L2-resident working set ~4MB sliding window).
__global__ __launch_bounds__(256) void main_kernel(const float* __restrict__ xmain,
                                                   const unsigned short* __restrict__ auxc,
                                                   float* __restrict__ out) {
    const int bid = blockIdx.x;                      // 2048 blocks, launched linear
    const int swz = ((bid & 7) << 8) | (bid >> 3);   // XCD x -> swz in [x*256, x*256+256)
    const int t   = swz >> 4;                        // 16 consecutive t per XCD
    const int r4  = swz & 15;
    const int eb  = (r4 & 3) * 128;
    const int mb  = (r4 >> 2) * 128;
    const int lane = threadIdx.x & 63, wid = threadIdx.x >> 6;
    const int wm = (wid & 1) * 64;
    const int we = (wid >> 1) * 64;
    const int l15 = lane & 15, lg = lane >> 4;

    const float* At = xmain + (size_t)t * M_DIM * K_DIM;
    const unsigned short* Bt = auxc + (size_t)t * AUX_T_STRIDE;

    f32x4 acc[4][4];
#pragma unroll
    for (int i = 0; i < 4; ++i)
#pragma unroll
        for (int j = 0; j < 4; ++j) acc[i][j] = (f32x4)0.0f;

#define MAIN_LOAD(afd, m0d, m1d, ksv)                                                      \
    do {                                                                                   \
        _Pragma("unroll") for (int i = 0; i < 4; ++i)                                      \
            afd[i] = *reinterpret_cast<const bf16x8*>(                                     \
                Bt + (size_t)((ksv) * 4 + lg) * CHUNK_G_STRIDE                             \
                   + (size_t)(eb + we + i * 16 + l15) * 8);                                \
        _Pragma("unroll") for (int j = 0; j < 4; ++j) {                                    \
            const float* p = At + (size_t)(mb + wm + j * 16 + l15) * K_DIM                 \
                           + (ksv) * 32 + lg * 8;                                          \
            m0d[j] = *reinterpret_cast<const f32x4*>(p);                                   \
            m1d[j] = *reinterpret_cast<const f32x4*>(p + 4);                               \
        }                                                                                  \
    } while (0)

#define MAIN_COMPUTE(afd, m0d, m1d)                                                        \
    do {                                                                                   \
        bf16x8 mf[4];                                                                      \
        _Pragma("unroll") for (int j = 0; j < 4; ++j) {                                    \
            uint4v w;                                                                      \
            w.x = pack2(m0d[j].x, m0d[j].y); w.y = pack2(m0d[j].z, m0d[j].w);              \
            w.z = pack2(m1d[j].x, m1d[j].y); w.w = pack2(m1d[j].z, m1d[j].w);              \
            mf[j] = __builtin_bit_cast(bf16x8, w);                                         \
        }                                                                                  \
        _Pragma("unroll") for (int i = 0; i < 4; ++i)                                      \
            _Pragma("unroll") for (int j = 0; j < 4; ++j)                                  \
                acc[i][j] = __builtin_amdgcn_mfma_f32_16x16x32_bf16(afd[i], mf[j], acc[i][j], 0, 0, 0); \
    } while (0)

    bf16x8 afA[4], afB[4];
    f32x4 m0A[4], m1A[4], m0B[4], m1B[4];
    MAIN_LOAD(afA, m0A, m1A, 0);
#pragma unroll
    for (int ks = 0; ks < 8; ks += 2) {
        MAIN_LOAD(afB, m0B, m1B, ks + 1);
        MAIN_COMPUTE(afA, m0A, m1A);
        if (ks + 2 < 8) { MAIN_LOAD(afA, m0A, m1A, ks + 2); }
        MAIN_COMPUTE(afB, m0B, m1B);
    }
#undef MAIN_LOAD
#undef MAIN_COMPUTE

#pragma unroll
    for (int i = 0; i < 4; ++i) {
        int e0 = eb + we + i * 16 + lg * 4;   // 4 consecutive e -> float4 store
#pragma unroll
        for (int j = 0; j < 4; ++j) {
            int m = mb + wm + j * 16 + l15;
            *reinterpret_cast<f32x4*>(out + (size_t)t * M_DIM * DENSE + (size_t)m * DENSE + e0) = acc[i][j];
        }
    }
}

extern "C" void kernel_launch(void* const* d_in, const int* in_sizes, int n_in,
                              void* d_out, int out_size, void* d_ws, size_t ws_size,
                              hipStream_t stream) {
    const float* x_main = (const float*)d_in[0];   // [1,128,512,256]
    const float* x_aux  = (const float*)d_in[1];   // [256,128,256]
    const float* W      = (const float*)d_in[2];   // [256,512]
    const float* b      = (const float*)d_in[3];   // [512]
    float* out = (float*)d_out;                    // [1,128,512,512,1]

    unsigned short* Wc   = (unsigned short*)d_ws;                       // 256 KiB
    unsigned short* auxc = (unsigned short*)((char*)d_ws + (1 << 19));  // 33.6 MiB

    wchunk_kernel<<<64, 256, 0, stream>>>(W, Wc);
    aux_kernel<<<dim3(2, 128), 512, 0, stream>>>(x_aux, Wc, b, auxc);
    main_kernel<<<2048, 256, 0, stream>>>(x_main, auxc, out);
}

// Round 3
// 257.114 us; speedup vs baseline: 1.2326x; 1.1676x over previous
//
#include <hip/hip_runtime.h>

// SLAM layer: out[1,T,M,E,1] = (main[T,M,K] @ relu(x_aux[K,T,Da] @ W[Da,E] + b)[K,T,E] per t)
// T=128, M=512, K=256, Da=256, E=512.
// R3: kill the strided-gather pathology. x_main pre-converted to bf16 chunk layout via
// LDS transpose; main GEMM loads both operands as contiguous 256B chunk runs. aux rebuilt
// lean (acc[4][4], 4 waves/SIMD, conflict-free LDS staging of x_aux).

typedef __attribute__((ext_vector_type(8))) short  bf16x8;   // MFMA A/B frag (4 VGPR)
typedef __attribute__((ext_vector_type(4))) float  f32x4;    // MFMA C/D frag
typedef __attribute__((ext_vector_type(4))) unsigned int uint4v;
typedef __attribute__((ext_vector_type(2))) unsigned int uint2v;

#define T_DIM 128
#define M_DIM 512
#define K_DIM 256
#define DA    256
#define DENSE 512
// chunk layouts (bf16): auxc (t,k,e) -> t*131072 + (k>>3)*4096 + e*8 + (k&7)
//                       xmc  (t,m,k) -> t*131072 + (k>>3)*4096 + m*8 + (k&7)
#define CHUNK_T_STRIDE 131072
#define CHUNK_G_STRIDE 4096

__device__ __forceinline__ unsigned short f2bf(float f) {
    unsigned u = __builtin_bit_cast(unsigned, f);
    unsigned r = (u + 0x7fffu + ((u >> 16) & 1u)) >> 16;   // RNE
    return (unsigned short)r;
}
__device__ __forceinline__ unsigned pack2(float lo, float hi) {
    return (unsigned)f2bf(lo) | ((unsigned)f2bf(hi) << 16);
}

// ---------------- Kernel 0: W [Da][E] f32 -> Wc bf16 chunks [g=Da/8][E][8] ----------------
__global__ __launch_bounds__(256) void wchunk_kernel(const float* __restrict__ W,
                                                     unsigned short* __restrict__ Wc) {
    int c = blockIdx.x * 256 + threadIdx.x;   // chunk id = g*DENSE + e
    int g = c >> 9;
    int e = c & 511;
    float f[8];
#pragma unroll
    for (int j = 0; j < 8; ++j) f[j] = W[(g * 8 + j) * DENSE + e];
    uint4v w;
    w.x = pack2(f[0], f[1]); w.y = pack2(f[2], f[3]);
    w.z = pack2(f[4], f[5]); w.w = pack2(f[6], f[7]);
    *reinterpret_cast<uint4v*>(Wc + (size_t)c * 8) = w;
}

// ---------------- Kernel 0b: x_main [T][M][K] f32 -> xmc bf16 chunks ----------------------
// Block = (t, 64 m-rows). Read rows coalesced (1KB each), XOR-swizzled LDS transpose,
// write 16B chunks with 64-lane-contiguous (1KB) runs.
__global__ __launch_bounds__(256) void xmchunk_kernel(const float* __restrict__ xmain,
                                                      unsigned short* __restrict__ xmc) {
    __shared__ unsigned short lds[64 * 256];  // 32 KB; 16B-unit XOR swizzle byte^=((row&7)<<4)
    const int mb = blockIdx.x * 64;
    const int t  = blockIdx.y;
    const int tid = threadIdx.x, lane = tid & 63, wid = tid >> 6;
    char* ldsb = reinterpret_cast<char*>(lds);
#pragma unroll
    for (int j = 0; j < 16; ++j) {
        int mr = wid + 4 * j;                  // row within tile
        const float* src = xmain + ((size_t)(t * M_DIM + mb + mr)) * K_DIM + lane * 4;
        f32x4 v = *reinterpret_cast<const f32x4*>(src);
        uint2v o; o.x = pack2(v.x, v.y); o.y = pack2(v.z, v.w);
        int bofs = mr * 512 + ((lane * 8) ^ ((mr & 7) << 4));
        *reinterpret_cast<uint2v*>(ldsb + bofs) = o;
    }
    __syncthreads();
#pragma unroll
    for (int i = 0; i < 8; ++i) {
        int g = wid * 8 + i;                   // k-group 0..31; row = lane (m_local)
        int bofs = lane * 512 + ((g * 16) ^ ((lane & 7) << 4));
        uint4v c = *reinterpret_cast<const uint4v*>(ldsb + bofs);
        *reinterpret_cast<uint4v*>(xmc + (size_t)t * CHUNK_T_STRIDE + (size_t)g * CHUNK_G_STRIDE
                                   + (size_t)(mb + lane) * 8) = c;
    }
}

// ---------------- Kernel 1: aux GEMM v3 ----------------------------------------------------
// Block = (t, kb 64, eb 256): 256 threads, 4 waves each 64k x 64e, acc[4][4].
// x_aux tile staged to LDS in chunk-major rows ([k][33 x 16B], 528B stride: write
// contiguous, frag-read 2-way-free banks). Wc frag loads double-buffered (L2-resident).
__global__ __launch_bounds__(256) void aux_kernel(const float* __restrict__ xaux,
                                                  const unsigned short* __restrict__ Wc,
                                                  const float* __restrict__ bias,
                                                  unsigned short* __restrict__ auxc) {
    __shared__ unsigned short xa[64 * 264];   // 33792 B
    const int bid = blockIdx.x;               // 1024 blocks
    const int swz = (bid & 7) * 128 + (bid >> 3);   // XCD-grouped, bijective (1024%8==0)
    const int t  = swz >> 3;
    const int r  = swz & 7;
    const int kb = (r >> 1) * 64;
    const int eb = (r & 1) * 256;
    const int tid = threadIdx.x, lane = tid & 63, wid = tid >> 6;
    const int l15 = lane & 15, lg = lane >> 4;
    char* xab = reinterpret_cast<char*>(xa);

    // ---- stage x_aux[t][kb..kb+64][0..256) -> LDS bf16, row k: 33x16B chunks ----
#pragma unroll
    for (int j = 0; j < 16; ++j) {
        int kr = wid + 4 * j;
        const float* src = xaux + ((size_t)(kb + kr) * T_DIM + t) * DA + lane * 4;
        f32x4 v = *reinterpret_cast<const f32x4*>(src);
        uint2v o; o.x = pack2(v.x, v.y); o.y = pack2(v.z, v.w);
        *reinterpret_cast<uint2v*>(xab + kr * 528 + lane * 8) = o;
    }
    __syncthreads();

    const int we = wid * 64;
    f32x4 acc[4][4];
#pragma unroll
    for (int i = 0; i < 4; ++i)
#pragma unroll
        for (int j = 0; j < 4; ++j) acc[i][j] = (f32x4)0.0f;

#define AUX_LOAD_WF(dst, dsv)                                                              \
    do {                                                                                   \
        _Pragma("unroll") for (int j = 0; j < 4; ++j) {                                    \
            int e = eb + we + j * 16 + l15;                                                \
            dst[j] = *reinterpret_cast<const bf16x8*>(                                     \
                Wc + (size_t)((dsv) * 4 + lg) * CHUNK_G_STRIDE + (size_t)e * 8);           \
        }                                                                                  \
    } while (0)

#define AUX_COMPUTE(wfc, dsv)                                                              \
    do {                                                                                   \
        bf16x8 xf[4];                                                                      \
        _Pragma("unroll") for (int i = 0; i < 4; ++i)                                      \
            xf[i] = *reinterpret_cast<const bf16x8*>(                                      \
                xab + (i * 16 + l15) * 528 + ((dsv) * 4 + lg) * 16);                       \
        _Pragma("unroll") for (int i = 0; i < 4; ++i)                                      \
            _Pragma("unroll") for (int j = 0; j < 4; ++j)                                  \
                acc[i][j] = __builtin_amdgcn_mfma_f32_16x16x32_bf16(xf[i], wfc[j], acc[i][j], 0, 0, 0); \
    } while (0)

    bf16x8 wfA[4], wfB[4];
    AUX_LOAD_WF(wfA, 0);
#pragma unroll
    for (int ds = 0; ds < 8; ds += 2) {
        AUX_LOAD_WF(wfB, ds + 1);
        AUX_COMPUTE(wfA, ds);
        if (ds + 2 < 8) { AUX_LOAD_WF(wfA, ds + 2); }
        AUX_COMPUTE(wfB, ds + 1);
    }
#undef AUX_LOAD_WF
#undef AUX_COMPUTE

    // ---- epilogue: +bias, relu, pack 4 bf16 -> chunk-layout store ----
#pragma unroll
    for (int i = 0; i < 4; ++i) {
        int k0 = kb + i * 16 + lg * 4;        // 4 acc regs = 4 consecutive k; k0&7 in {0,4}
#pragma unroll
        for (int j = 0; j < 4; ++j) {
            int e = eb + we + j * 16 + l15;
            float bv = bias[e];
            float v0 = fmaxf(acc[i][j].x + bv, 0.0f);
            float v1 = fmaxf(acc[i][j].y + bv, 0.0f);
            float v2 = fmaxf(acc[i][j].z + bv, 0.0f);
            float v3 = fmaxf(acc[i][j].w + bv, 0.0f);
            uint2 o; o.x = pack2(v0, v1); o.y = pack2(v2, v3);
            size_t idx = (size_t)t * CHUNK_T_STRIDE + (size_t)(k0 >> 3) * CHUNK_G_STRIDE
                       + (size_t)e * 8 + (k0 & 7);
            *reinterpret_cast<uint2*>(auxc + idx) = o;
        }
    }
}

// ---------------- Kernel 2: main GEMM v3 (batched over t) ----------------------------------
// D[e][m] = sum_k auxc[k][e] * xmc[m][k]; both operands bf16 chunks -> every wave-load is
// 4x 256B contiguous runs. Register double-buffer; XCD swizzle groups 16 blocks per t.
__global__ __launch_bounds__(256) void main_kernel(const unsigned short* __restrict__ xmc,
                                                   const unsigned short* __restrict__ auxc,
                                                   float* __restrict__ out) {
    const int bid = blockIdx.x;                      // 2048 blocks
    const int swz = ((bid & 7) << 8) | (bid >> 3);   // XCD-grouped, bijective
    const int t   = swz >> 4;
    const int r4  = swz & 15;
    const int eb  = (r4 & 3) * 128;
    const int mb  = (r4 >> 2) * 128;
    const int lane = threadIdx.x & 63, wid = threadIdx.x >> 6;
    const int wm = (wid & 1) * 64;
    const int we = (wid >> 1) * 64;
    const int l15 = lane & 15, lg = lane >> 4;

    const unsigned short* At = auxc + (size_t)t * CHUNK_T_STRIDE;   // A-op rows = e
    const unsigned short* Bt = xmc  + (size_t)t * CHUNK_T_STRIDE;   // B-op cols = m

    f32x4 acc[4][4];
#pragma unroll
    for (int i = 0; i < 4; ++i)
#pragma unroll
        for (int j = 0; j < 4; ++j) acc[i][j] = (f32x4)0.0f;

#define MAIN_LOAD(afd, mfd, ksv)                                                           \
    do {                                                                                   \
        _Pragma("unroll") for (int i = 0; i < 4; ++i)                                      \
            afd[i] = *reinterpret_cast<const bf16x8*>(                                     \
                At + (size_t)((ksv) * 4 + lg) * CHUNK_G_STRIDE                             \
                   + (size_t)(eb + we + i * 16 + l15) * 8);                                \
        _Pragma("unroll") for (int j = 0; j < 4; ++j)                                      \
            mfd[j] = *reinterpret_cast<const bf16x8*>(                                     \
                Bt + (size_t)((ksv) * 4 + lg) * CHUNK_G_STRIDE                             \
                   + (size_t)(mb + wm + j * 16 + l15) * 8);                                \
    } while (0)

#define MAIN_COMPUTE(afd, mfd)                                                             \
    do {                                                                                   \
        _Pragma("unroll") for (int i = 0; i < 4; ++i)                                      \
            _Pragma("unroll") for (int j = 0; j < 4; ++j)                                  \
                acc[i][j] = __builtin_amdgcn_mfma_f32_16x16x32_bf16(afd[i], mfd[j], acc[i][j], 0, 0, 0); \
    } while (0)

    bf16x8 afA[4], afB[4], mfA[4], mfB[4];
    MAIN_LOAD(afA, mfA, 0);
#pragma unroll
    for (int ks = 0; ks < 8; ks += 2) {
        MAIN_LOAD(afB, mfB, ks + 1);
        MAIN_COMPUTE(afA, mfA);
        if (ks + 2 < 8) { MAIN_LOAD(afA, mfA, ks + 2); }
        MAIN_COMPUTE(afB, mfB);
    }
#undef MAIN_LOAD
#undef MAIN_COMPUTE

#pragma unroll
    for (int i = 0; i < 4; ++i) {
        int e0 = eb + we + i * 16 + lg * 4;   // 4 consecutive e -> float4 store
#pragma unroll
        for (int j = 0; j < 4; ++j) {
            int m = mb + wm + j * 16 + l15;
            *reinterpret_cast<f32x4*>(out + (size_t)t * M_DIM * DENSE + (size_t)m * DENSE + e0) = acc[i][j];
        }
    }
}

extern "C" void kernel_launch(void* const* d_in, const int* in_sizes, int n_in,
                              void* d_out, int out_size, void* d_ws, size_t ws_size,
                              hipStream_t stream) {
    const float* x_main = (const float*)d_in[0];   // [1,128,512,256]
    const float* x_aux  = (const float*)d_in[1];   // [256,128,256]
    const float* W      = (const float*)d_in[2];   // [256,512]
    const float* b      = (const float*)d_in[3];   // [512]
    float* out = (float*)d_out;                    // [1,128,512,512,1]

    // ws layout: Wc 256KiB @0 ; auxc 32MiB @ 1<<19 ; xmc 32MiB @ (1<<19)+(1<<25). Total 64.5MiB.
    unsigned short* Wc   = (unsigned short*)d_ws;
    unsigned short* auxc = (unsigned short*)((char*)d_ws + (1u << 19));
    unsigned short* xmc  = (unsigned short*)((char*)d_ws + (1u << 19) + (1u << 25));

    wchunk_kernel<<<64, 256, 0, stream>>>(W, Wc);
    xmchunk_kernel<<<dim3(8, 128), 256, 0, stream>>>(x_main, xmc);
    aux_kernel<<<1024, 256, 0, stream>>>(x_aux, Wc, b, auxc);
    main_kernel<<<2048, 256, 0, stream>>>(xmc, auxc, out);
}